// Round 11
// baseline (97.272 us; speedup 1.0000x reference)
//
#include <hip/hip_runtime.h>
#include <stdint.h>

// Batched kNN (k=20, D=3) vs fp32 numpy/XLA-CPU reference. Numerics LOCKED
// (R4 passed absmax=0):
//   sq  = ((x0*x0 + x1*x1) + x2*x2)          plain chain
//   dot = fmaf(x2,y2, fmaf(x1,y1, x0*y0))    FMA ascending-k
//   d   = (sq_i + sq_j) - 2*dot
// fp32 ties re-ranked by exact fp64 distance, then ORIGINAL index.
//
// R11: padded cloud-aligned candidate array.
//  - scatter kernel packs each cloud c into pts[c*1792 .. ], float4(x,y,z,sq),
//    sentinel (1e18,1e18,1e18,3e36) in the tail -> finite-huge keys, no NaN.
//  - main kernel: cbase = batch[i]*1792 (no wave_lower_bound, ~2k serial
//    cycles gone), no bounds check in build (sentinels auto-excluded by <=T),
//    1 dwordx4 load + ~11 VALU per candidate (was 3 loads + ~19).
//  - idxmap[padded] -> original index for output + tie-break.
//  R10's bitonic-T + compaction + exact P3 refinement unchanged.

#define MAXC 28            // candidates/lane
#define PADC 1792          // MAXC*64; cloud capacity (actual ~1536 +- 37)
#define NCLOUDS 8          // reference constant NUM_CLOUDS
#define ROWS_PER_BLOCK 4   // 1 row per wave, 256-thread blocks

__device__ __forceinline__ unsigned int map32(float d) {
    unsigned int u = __float_as_uint(d);
    return u ^ (unsigned int)(((int)u >> 31) | 0x80000000);
}

__device__ __forceinline__ unsigned long long map64(double d) {
    unsigned long long u = __double_as_longlong(d);
    return u ^ (unsigned long long)(((long long)u >> 63) |
                                    (long long)0x8000000000000000ull);
}

__device__ __forceinline__ unsigned int umin2(unsigned int a, unsigned int b) {
    return a < b ? a : b;
}
__device__ __forceinline__ unsigned int umax2(unsigned int a, unsigned int b) {
    return a > b ? a : b;
}

// Full-wave unsigned-min via DPP (fallback path only).
__device__ __forceinline__ unsigned int wave_umin_dpp(unsigned int v) {
    int x = (int)v, t;
    t = __builtin_amdgcn_update_dpp(-1, x, 0x111, 0xf, 0xf, false);
    x = (int)umin2((unsigned int)x, (unsigned int)t);
    t = __builtin_amdgcn_update_dpp(-1, x, 0x112, 0xf, 0xf, false);
    x = (int)umin2((unsigned int)x, (unsigned int)t);
    t = __builtin_amdgcn_update_dpp(-1, x, 0x114, 0xf, 0xf, false);
    x = (int)umin2((unsigned int)x, (unsigned int)t);
    t = __builtin_amdgcn_update_dpp(-1, x, 0x118, 0xf, 0xf, false);
    x = (int)umin2((unsigned int)x, (unsigned int)t);
    t = __builtin_amdgcn_update_dpp(-1, x, 0x142, 0xa, 0xf, false);
    x = (int)umin2((unsigned int)x, (unsigned int)t);
    t = __builtin_amdgcn_update_dpp(-1, x, 0x143, 0xc, 0xf, false);
    x = (int)umin2((unsigned int)x, (unsigned int)t);
    return (unsigned int)__builtin_amdgcn_readlane(x, 63);
}

__global__ void init_bounds_kernel(int* __restrict__ starts,
                                   int* __restrict__ ends, int n) {
    int c = threadIdx.x;  // 1 block, 256 threads
    starts[c] = n;        // empty cloud -> len <= 0 -> all sentinel
    ends[c] = 0;
}

__global__ void bounds_kernel(const int* __restrict__ batch, int n,
                              int* __restrict__ starts, int* __restrict__ ends) {
    int j = blockIdx.x * blockDim.x + threadIdx.x;
    if (j >= n) return;
    int b = batch[j];
    if (j == 0 || batch[j - 1] != b) starts[b] = j;
    if (j == n - 1 || batch[j + 1] != b) ends[b] = j + 1;
}

__global__ void scatter_kernel(const float* __restrict__ x,
                               const int* __restrict__ starts,
                               const int* __restrict__ ends,
                               float4* __restrict__ pts,
                               int* __restrict__ idxmap) {
#pragma clang fp contract(off)
    int p = blockIdx.x * blockDim.x + threadIdx.x;
    if (p >= NCLOUDS * PADC) return;
    int c = p / PADC;
    int r = p - c * PADC;
    int s = starts[c];
    int j = s + r;
    if (j < ends[c]) {
        float x0 = x[3 * j + 0];
        float x1 = x[3 * j + 1];
        float x2 = x[3 * j + 2];
        float sq = x0 * x0 + x1 * x1 + x2 * x2;  // plain chain (LOCKED)
        pts[p] = make_float4(x0, x1, x2, sq);
        idxmap[p] = j;
    } else {
        pts[p] = make_float4(1e18f, 1e18f, 1e18f, 3e36f);  // finite-huge
        idxmap[p] = -1;
    }
}

__global__ __launch_bounds__(256) void knn_fused_kernel(
        const float4* __restrict__ pts,
        const int* __restrict__ idxmap,
        const int* __restrict__ batch,
        const int* __restrict__ starts,
        int k, int n,
        int* __restrict__ out) {
#pragma clang fp contract(off)
    __shared__ int coll[ROWS_PER_BLOCK][64];
    const int wave = threadIdx.x >> 6;
    const int lane = threadIdx.x & 63;
    const int i = blockIdx.x * ROWS_PER_BLOCK + wave;  // one row per wave
    if (i >= n) return;

    const int b = batch[i];
    const int cbase = b * PADC;
    const int ip = cbase + (i - starts[b]);  // i's padded slot
    const float4 wi4 = pts[ip];
    const float xi0 = wi4.x, xi1 = wi4.y, xi2 = wi4.z, sqi = wi4.w;

    // Build u32 value keys; no bounds checks (sentinels -> huge keys).
    unsigned int slots[MAXC];
    unsigned int c0 = 0xFFFFFFFFu, c1 = 0xFFFFFFFFu;
    unsigned int c2 = 0xFFFFFFFFu, c3 = 0xFFFFFFFFu;
#pragma unroll
    for (int t = 0; t < MAXC; ++t) {
        const int jp = cbase + lane + t * 64;
        const float4 wj = pts[jp];
        float dot = __builtin_fmaf(xi2, wj.z,
                    __builtin_fmaf(xi1, wj.y, xi0 * wj.x));
        float d = (sqi + wj.w) - 2.0f * dot;
        unsigned int key = map32(d);
        slots[t] = key;
        switch (t & 3) {
            case 0: c0 = umin2(c0, key); break;
            case 1: c1 = umin2(c1, key); break;
            case 2: c2 = umin2(c2, key); break;
            default: c3 = umin2(c3, key); break;
        }
    }
    unsigned int localmin = umin2(umin2(c0, c1), umin2(c2, c3));

    // Bitonic sort of the 64 column-mins; T = k-th smallest (upper bound on
    // the k-th smallest candidate).
    unsigned int v = localmin;
#pragma unroll
    for (int kk = 2; kk <= 64; kk <<= 1) {
#pragma unroll
        for (int j = kk >> 1; j > 0; j >>= 1) {
            unsigned int p = (unsigned int)__shfl_xor((int)v, j);
            bool keepMin = (((lane & j) == 0) == ((lane & kk) == 0));
            v = keepMin ? umin2(v, p) : umax2(v, p);
        }
    }
    unsigned int T = (unsigned int)__builtin_amdgcn_readlane((int)v, k - 1);

    // Phase 2: compact padded indices of candidates with key <= T.
    int base = 0;
#pragma unroll
    for (int t = 0; t < MAXC; ++t) {
        bool hit = (slots[t] <= T);  // sentinels/pads always > T
        unsigned long long bal = __ballot(hit);
        int off = base + __builtin_amdgcn_mbcnt_hi(
                             (unsigned int)(bal >> 32),
                             __builtin_amdgcn_mbcnt_lo((unsigned int)bal, 0));
        if (hit && off < 64) coll[wave][off] = cbase + lane + t * 64;
        base += (int)__popcll(bal);
    }

    if (base > 64) {
        // Fallback (wave-uniform, astronomically rare): exact threshold-
        // ascent -> T = k-th distinct value, then recompact.
        unsigned int thrp1 = 0;
        for (int r = 0; r < k; ++r) {
            unsigned int m0 = slots[0] - thrp1, m1 = slots[1] - thrp1;
            unsigned int m2 = slots[2] - thrp1, m3 = slots[3] - thrp1;
#pragma unroll
            for (int t = 4; t < MAXC; t += 4) {
                m0 = umin2(m0, slots[t + 0] - thrp1);
                m1 = umin2(m1, slots[t + 1] - thrp1);
                m2 = umin2(m2, slots[t + 2] - thrp1);
                m3 = umin2(m3, slots[t + 3] - thrp1);
            }
            unsigned int lm = umin2(umin2(m0, m1), umin2(m2, m3));
            T = wave_umin_dpp(lm) + thrp1;
            thrp1 = T + 1;
        }
        base = 0;
#pragma unroll
        for (int t = 0; t < MAXC; ++t) {
            bool hit = (slots[t] <= T);
            unsigned long long bal = __ballot(hit);
            int off = base + __builtin_amdgcn_mbcnt_hi(
                                 (unsigned int)(bal >> 32),
                                 __builtin_amdgcn_mbcnt_lo((unsigned int)bal, 0));
            if (hit && off < 64) coll[wave][off] = cbase + lane + t * 64;
            base += (int)__popcll(bal);
        }
    }
    const int cnt = base < 64 ? base : 64;  // wave-uniform

    // Phase 3: refinement — rank collected by (fp32key, fp64 dist, orig idx).
    const bool valid = (lane < cnt);
    const int jp = valid ? coll[wave][lane] : cbase;
    unsigned int v32 = 0xFFFFFFFFu;
    unsigned long long m64 = ~0ull;
    int oidx = 0;
    if (valid) {
        const float4 wj = pts[jp];
        oidx = idxmap[jp];
        float dot = __builtin_fmaf(xi2, wj.z,
                    __builtin_fmaf(xi1, wj.y, xi0 * wj.x));
        float d = (sqi + wj.w) - 2.0f * dot;
        v32 = map32(d);
        // exact fp64 (products of fp32 are exact in double)
        double q0 = (double)xi0 * (double)xi0;
        double q1 = (double)xi1 * (double)xi1;
        double q2 = (double)xi2 * (double)xi2;
        double sqdi = (q0 + q1) + q2;
        double w0 = (double)wj.x * (double)wj.x;
        double w1 = (double)wj.y * (double)wj.y;
        double w2 = (double)wj.z * (double)wj.z;
        double sqdj = (w0 + w1) + w2;
        double p0 = (double)xi0 * (double)wj.x;
        double p1 = (double)xi1 * (double)wj.y;
        double p2 = (double)xi2 * (double)wj.z;
        double dot64 = (p0 + p1) + p2;
        double d64 = (sqdi + sqdj) - 2.0 * dot64;
        m64 = map64(d64);
    }

    int pos = 0;
    for (int s = 0; s < cnt; ++s) {
        unsigned int vs = (unsigned int)__shfl((int)v32, s);
        unsigned long long ms = __shfl(m64, s);
        int is_ = __shfl(oidx, s);
        bool less = (vs < v32) ||
                    (vs == v32 && (ms < m64 || (ms == m64 && is_ < oidx)));
        pos += less ? 1 : 0;
    }

    if (valid && pos < k) out[(long long)i * k + pos] = oidx;
}

extern "C" void kernel_launch(void* const* d_in, const int* in_sizes, int n_in,
                              void* d_out, int out_size, void* d_ws, size_t ws_size,
                              hipStream_t stream) {
    const float* x = (const float*)d_in[0];
    const int* batch = (const int*)d_in[1];
    const int n = in_sizes[1];            // 12288 points
    const int k = out_size / n;           // 20
    int* out = (int*)d_out;

    char* ws = (char*)d_ws;
    float4* pts = (float4*)ws;            ws += (size_t)NCLOUDS * PADC * sizeof(float4);
    int* idxmap = (int*)ws;               ws += (size_t)NCLOUDS * PADC * sizeof(int);
    int* starts = (int*)ws;               ws += 256 * sizeof(int);
    int* ends = (int*)ws;

    init_bounds_kernel<<<1, 256, 0, stream>>>(starts, ends, n);
    bounds_kernel<<<(n + 255) / 256, 256, 0, stream>>>(batch, n, starts, ends);
    scatter_kernel<<<(NCLOUDS * PADC + 255) / 256, 256, 0, stream>>>(x, starts, ends, pts, idxmap);
    const int blocks = (n + ROWS_PER_BLOCK - 1) / ROWS_PER_BLOCK;
    knn_fused_kernel<<<blocks, 64 * ROWS_PER_BLOCK, 0, stream>>>(pts, idxmap, batch, starts, k, n, out);
}